// Round 6
// baseline (230.666 us; speedup 1.0000x reference)
//
#include <hip/hip_runtime.h>

#define B_     16
#define D_     256
#define HEADS_ 8
#define H_     56
#define W_     56
#define L_     3136
#define LDK    40    // padded LDS row stride for 32-col bf16 tiles (80 B, 16B-aligned, 2-way max)
#define LDQ    264   // padded LDS row stride for qk rows (256 cols)

typedef short short8 __attribute__((ext_vector_type(8)));
typedef float f32x4  __attribute__((ext_vector_type(4)));

__device__ __forceinline__ unsigned short f2bf(float f) {
    union { float f; unsigned u; } c; c.f = f;
    unsigned u = c.u;
    u += 0x7fffu + ((u >> 16) & 1u);   // RNE
    return (unsigned short)(u >> 16);
}

// ---------------------------------------------------------------------------
// x [b][c][l] fp32 -> Xt [b][l][c] bf16  (64x64 LDS tile transpose) [R3-proven]
// ---------------------------------------------------------------------------
__global__ __launch_bounds__(256) void transpose_x_kernel(
    const float* __restrict__ x, unsigned short* __restrict__ Xt)
{
    __shared__ float tile[64][65];
    const int bb = blockIdx.z;
    const int c0 = blockIdx.y * 64;
    const int l0 = blockIdx.x * 64;
    const int t  = threadIdx.x;
    const int g4 = (t & 15) * 4;
    const int rr = t >> 4;

    const float* xb = x + ((size_t)bb * D_ + c0) * L_ + l0;
#pragma unroll
    for (int i = 0; i < 4; ++i) {
        const int c = rr + i * 16;
        float4 v = *(const float4*)(xb + (size_t)c * L_ + g4);
        *(float4*)&tile[c][g4] = v;
    }
    __syncthreads();
    unsigned short* Xb = Xt + ((size_t)bb * L_ + l0) * D_ + c0;
#pragma unroll
    for (int i = 0; i < 4; ++i) {
        const int l = rr + i * 16;
        uint2 o;
        o.x = (unsigned)f2bf(tile[g4 + 0][l]) | ((unsigned)f2bf(tile[g4 + 1][l]) << 16);
        o.y = (unsigned)f2bf(tile[g4 + 2][l]) | ((unsigned)f2bf(tile[g4 + 3][l]) << 16);
        *(uint2*)(Xb + (size_t)l * D_ + g4) = o;
    }
}

// ---------------------------------------------------------------------------
// Wv, Wproj fp32 -> bf16
// ---------------------------------------------------------------------------
__global__ __launch_bounds__(256) void convert_w_kernel(
    const float* __restrict__ w0, const float* __restrict__ w1,
    unsigned short* __restrict__ o0, unsigned short* __restrict__ o1)
{
    const float* src = blockIdx.y ? w1 : w0;
    unsigned short* dst = blockIdx.y ? o1 : o0;
    const int i = (blockIdx.x * 256 + threadIdx.x) * 4;
    float4 v = *(const float4*)(src + i);
    uint2 o;
    o.x = (unsigned)f2bf(v.x) | ((unsigned)f2bf(v.y) << 16);
    o.y = (unsigned)f2bf(v.z) | ((unsigned)f2bf(v.w) << 16);
    *(uint2*)(dst + i) = o;
}

// ---------------------------------------------------------------------------
// qk[b,h,c] = sum_n q[b,h,n]*Wk[h*32+n,c]; rows 8..15 zero (A-tile padding)
// ---------------------------------------------------------------------------
__global__ __launch_bounds__(256) void qk_kernel(
    const float* __restrict__ q, const float* __restrict__ Wk,
    unsigned short* __restrict__ qkb)
{
    const int h = blockIdx.x;
    const int b = blockIdx.y;
    const int c = threadIdx.x;
    float s = 0.f;
#pragma unroll
    for (int n = 0; n < 32; ++n)
        s = fmaf(q[b * D_ + h * 32 + n], Wk[(size_t)(h * 32 + n) * D_ + c], s);
    qkb[((size_t)b * 16 + h) * D_ + c]     = f2bf(s);
    qkb[((size_t)b * 16 + 8 + h) * D_ + c] = 0;
}

// ---------------------------------------------------------------------------
// V projection + S.  BM=256 (x read once), BN=64, BK=32, 4 waves.
// Double-buffered LDS (Wv + Xt tiles), register-prefetched globals,
// ONE barrier per kt. Wave w: d=[64w,64w+64) -> 16 V-MFMA + 1 S-MFMA per kt.
// ---------------------------------------------------------------------------
__global__ __launch_bounds__(256, 2) void gemm_v_mfma(
    const unsigned short* __restrict__ Xt, const unsigned short* __restrict__ Wvb,
    const unsigned short* __restrict__ qkb,
    unsigned short* __restrict__ Vo, float* __restrict__ S)
{
    __shared__ unsigned short Wvs[2][256][LDK];  // 40 KB
    __shared__ unsigned short Xs[2][64][LDK];    // 10 KB
    __shared__ unsigned short Qs[16][LDQ];       // 8.25 KB

    const int bb = blockIdx.y;
    const int l0 = blockIdx.x * 64;
    const int t  = threadIdx.x;
    const int w    = t >> 6;
    const int lane = t & 63;
    const int col  = lane & 15;
    const int quad = lane >> 4;

    // stage qk once (16 rows x 256 cols): 16 shorts per thread
    {
        const int r  = t >> 4;
        const int c16 = (t & 15) * 16;
        const unsigned short* src = qkb + ((size_t)bb * 16 + r) * D_ + c16;
        *(uint4*)&Qs[r][c16]     = *(const uint4*)src;
        *(uint4*)&Qs[r][c16 + 8] = *(const uint4*)(src + 8);
    }

    const int srow = t >> 2;         // 0..63
    const int sch  = (t & 3) * 8;    // 0,8,16,24
    const unsigned short* xg = Xt + ((size_t)bb * L_ + l0 + srow) * D_ + sch;
    const unsigned short* wgv = Wvb + (size_t)srow * D_ + sch;

    uint4 pW[4], pX;
    pX = *(const uint4*)xg;
#pragma unroll
    for (int i = 0; i < 4; ++i)
        pW[i] = *(const uint4*)(wgv + (size_t)i * 64 * D_);

    f32x4 accV[4][4];
    f32x4 accS = (f32x4){0.f, 0.f, 0.f, 0.f};
#pragma unroll
    for (int mi = 0; mi < 4; ++mi)
#pragma unroll
        for (int ni = 0; ni < 4; ++ni) accV[mi][ni] = (f32x4){0.f, 0.f, 0.f, 0.f};

    for (int kt = 0; kt < 8; ++kt) {
        const int buf = kt & 1;
        *(uint4*)&Xs[buf][srow][sch] = pX;
#pragma unroll
        for (int i = 0; i < 4; ++i)
            *(uint4*)&Wvs[buf][srow + 64 * i][sch] = pW[i];
        __syncthreads();

        if (kt < 7) {   // prefetch next chunk; lands while MFMAs run
            pX = *(const uint4*)(xg + (kt + 1) * 32);
#pragma unroll
            for (int i = 0; i < 4; ++i)
                pW[i] = *(const uint4*)(wgv + (size_t)i * 64 * D_ + (kt + 1) * 32);
        }

        short8 av[4], bx[4], aq;
        aq = *(const short8*)&Qs[col][kt * 32 + quad * 8];
#pragma unroll
        for (int mi = 0; mi < 4; ++mi)
            av[mi] = *(const short8*)&Wvs[buf][w * 64 + mi * 16 + col][quad * 8];
#pragma unroll
        for (int ni = 0; ni < 4; ++ni)
            bx[ni] = *(const short8*)&Xs[buf][ni * 16 + col][quad * 8];

#pragma unroll
        for (int mi = 0; mi < 4; ++mi)
#pragma unroll
            for (int ni = 0; ni < 4; ++ni)
                accV[mi][ni] = __builtin_amdgcn_mfma_f32_16x16x32_bf16(
                    av[mi], bx[ni], accV[mi][ni], 0, 0, 0);
        accS = __builtin_amdgcn_mfma_f32_16x16x32_bf16(aq, bx[w], accS, 0, 0, 0);
    }

    // ---- V epilogue: Vo[((b*8+head)*L + l)*32 + (d&31)] ----
#pragma unroll
    for (int mi = 0; mi < 4; ++mi) {
        const int hh = w * 2 + (mi >> 1);
        const int dn = (mi & 1) * 16 + quad * 4;
#pragma unroll
        for (int ni = 0; ni < 4; ++ni) {
            unsigned short pk[4];
#pragma unroll
            for (int r = 0; r < 4; ++r) pk[r] = f2bf(accV[mi][ni][r]);
            const int l = l0 + ni * 16 + col;
            *(uint2*)(Vo + ((((size_t)(bb * HEADS_ + hh)) * L_ + l) << 5) + dn) =
                *(const uint2*)pk;
        }
    }

    // ---- S epilogue: wave w holds l-chunk ni=w; C rows 0..7 are heads ----
    if (quad < 2) {
        const int l = l0 + w * 16 + col;
#pragma unroll
        for (int r = 0; r < 4; ++r) {
            const int h = quad * 4 + r;
            S[(size_t)(bb * HEADS_ + h) * L_ + l] = accS[r];
        }
    }
}

// ---------------------------------------------------------------------------
// attend: LDS-staged, block = (8-row band, 8-ch group, b*h). [R3/R4-proven]
// ---------------------------------------------------------------------------
__global__ __launch_bounds__(256) void attend_kernel(
    const float* __restrict__ S, const unsigned short* __restrict__ Vo,
    const float* __restrict__ pos_emb, const float* __restrict__ Wlin,
    unsigned short* __restrict__ Om)
{
    __shared__ unsigned short Vs[10][58][8];
    __shared__ float Ss[10][58];

    const int band = blockIdx.x;
    const int half = blockIdx.y;
    const int bh   = blockIdx.z;
    const int y0   = band * 8;
    const int t    = threadIdx.x;

    const float* Sb = S + (size_t)bh * L_;
    for (int j = t; j < 580; j += 256) {
        const int row = j / 58, c = j - row * 58;
        const int gr = y0 - 1 + row, gc = c - 1;
        const bool in = (gr >= 0 && gr < H_ && gc >= 0 && gc < W_);
        Ss[row][c] = in ? Sb[gr * W_ + gc] : 0.f;
        uint4 vv = make_uint4(0u, 0u, 0u, 0u);
        if (in)
            vv = *(const uint4*)(Vo + (((size_t)bh * L_ + gr * W_ + gc) << 5) + half * 8);
        *(uint4*)&Vs[row][c][0] = vv;
    }
    __syncthreads();

    const float scale = Wlin[0] + Wlin[1] + Wlin[2] + Wlin[3];
    const float pe0 = pos_emb[0], pe1 = pos_emb[1], pe2 = pos_emb[2];
    const float pe3 = pos_emb[3], pe4 = pos_emb[4];
    const float bias[9] = {pe0, pe1, pe2, pe1, pe2, pe3, pe2, pe3, pe4};

    for (int p = t; p < 448; p += 256) {
        const int yl = p / 56, xx = p - yl * 56;
        const int lr = yl + 1, lc = xx + 1;

        float lg[9], m = -1e30f;
#pragma unroll
        for (int dy = 0; dy < 3; ++dy)
#pragma unroll
            for (int dx = 0; dx < 3; ++dx) {
                const int k = dy * 3 + dx;
                lg[k] = Ss[lr - 1 + dy][lc - 1 + dx] + bias[k];
                m = fmaxf(m, lg[k]);
            }
        float ssum = 0.f;
#pragma unroll
        for (int k = 0; k < 9; ++k) { lg[k] = __expf(lg[k] - m); ssum += lg[k]; }
        const float inv = scale / ssum;

        float om[8] = {0.f, 0.f, 0.f, 0.f, 0.f, 0.f, 0.f, 0.f};
#pragma unroll
        for (int dy = 0; dy < 3; ++dy)
#pragma unroll
            for (int dx = 0; dx < 3; ++dx) {
                const float wk = lg[dy * 3 + dx] * inv;
                const uint4 v = *(const uint4*)&Vs[lr - 1 + dy][lc - 1 + dx][0];
                const unsigned* u = (const unsigned*)&v;
#pragma unroll
                for (int i = 0; i < 4; ++i) {
                    union { unsigned uu; float f; } lo, hi;
                    lo.uu = u[i] << 16;
                    hi.uu = u[i] & 0xffff0000u;
                    om[2 * i]     = fmaf(wk, lo.f, om[2 * i]);
                    om[2 * i + 1] = fmaf(wk, hi.f, om[2 * i + 1]);
                }
            }

        unsigned short ob[8];
#pragma unroll
        for (int i = 0; i < 8; ++i) ob[i] = f2bf(om[i]);
        const int l = (y0 + yl) * W_ + xx;
        *(uint4*)(Om + (((size_t)bh * L_ + l) << 5) + half * 8) = *(const uint4*)ob;
    }
}

// ---------------------------------------------------------------------------
// out = Wproj @ Om.  Same structure as gemm_v: BM=256, BN=64, dbuf LDS,
// one barrier/kt. Om [b][h][l][32]: kt == head, staging fully contiguous.
// ---------------------------------------------------------------------------
__global__ __launch_bounds__(256, 3) void gemm_proj_mfma(
    const unsigned short* __restrict__ Om, const unsigned short* __restrict__ Wpb,
    float* __restrict__ Out)
{
    __shared__ unsigned short Wps[2][256][LDK];  // 40 KB
    __shared__ unsigned short Os[2][64][LDK];    // 10 KB

    const int bb = blockIdx.y;
    const int l0 = blockIdx.x * 64;
    const int t  = threadIdx.x;
    const int w    = t >> 6;
    const int lane = t & 63;
    const int col  = lane & 15;
    const int quad = lane >> 4;

    const int srow = t >> 2;
    const int sch  = (t & 3) * 8;
    const unsigned short* wgp = Wpb + (size_t)srow * D_ + sch;

    uint4 pW[4], pO;
    pO = *(const uint4*)(Om + ((((size_t)(bb * HEADS_)) * L_ + l0 + srow) << 5) + sch);
#pragma unroll
    for (int i = 0; i < 4; ++i)
        pW[i] = *(const uint4*)(wgp + (size_t)i * 64 * D_);

    f32x4 acc[4][4];
#pragma unroll
    for (int mi = 0; mi < 4; ++mi)
#pragma unroll
        for (int ni = 0; ni < 4; ++ni) acc[mi][ni] = (f32x4){0.f, 0.f, 0.f, 0.f};

    for (int kt = 0; kt < 8; ++kt) {
        const int buf = kt & 1;
        *(uint4*)&Os[buf][srow][sch] = pO;
#pragma unroll
        for (int i = 0; i < 4; ++i)
            *(uint4*)&Wps[buf][srow + 64 * i][sch] = pW[i];
        __syncthreads();

        if (kt < 7) {
            pO = *(const uint4*)(Om +
                ((((size_t)(bb * HEADS_ + kt + 1)) * L_ + l0 + srow) << 5) + sch);
#pragma unroll
            for (int i = 0; i < 4; ++i)
                pW[i] = *(const uint4*)(wgp + (size_t)i * 64 * D_ + (kt + 1) * 32);
        }

        short8 a[4], b[4];
#pragma unroll
        for (int mi = 0; mi < 4; ++mi)
            a[mi] = *(const short8*)&Wps[buf][w * 64 + mi * 16 + col][quad * 8];
#pragma unroll
        for (int ni = 0; ni < 4; ++ni)
            b[ni] = *(const short8*)&Os[buf][ni * 16 + col][quad * 8];

#pragma unroll
        for (int mi = 0; mi < 4; ++mi)
#pragma unroll
            for (int ni = 0; ni < 4; ++ni)
                acc[mi][ni] = __builtin_amdgcn_mfma_f32_16x16x32_bf16(
                    a[mi], b[ni], acc[mi][ni], 0, 0, 0);
    }

#pragma unroll
    for (int mi = 0; mi < 4; ++mi)
#pragma unroll
        for (int ni = 0; ni < 4; ++ni)
#pragma unroll
            for (int r = 0; r < 4; ++r) {
                const int d = w * 64 + mi * 16 + quad * 4 + r;
                const int l = l0 + ni * 16 + col;
                Out[((size_t)bb * D_ + d) * L_ + l] = acc[mi][ni][r];
            }
}

// ---------------------------------------------------------------------------
extern "C" void kernel_launch(void* const* d_in, const int* in_sizes, int n_in,
                              void* d_out, int out_size, void* d_ws, size_t ws_size,
                              hipStream_t stream)
{
    const float* x       = (const float*)d_in[0];
    const float* q       = (const float*)d_in[1];
    const float* Wk      = (const float*)d_in[2];
    const float* Wv      = (const float*)d_in[3];
    const float* pos_emb = (const float*)d_in[4];
    const float* Wlin    = (const float*)d_in[5];
    const float* Wproj   = (const float*)d_in[6];
    float* out = (float*)d_out;

    const size_t planeE = (size_t)B_ * D_ * L_;
    unsigned short* Xt  = (unsigned short*)d_ws;
    unsigned short* Vo  = Xt + planeE;
    unsigned short* Om  = Vo + planeE;
    unsigned short* Wvb = Om + planeE;
    unsigned short* Wpb = Wvb + D_ * D_;
    unsigned short* qkb = Wpb + D_ * D_;          // B*16*256
    float*          S   = (float*)(qkb + B_ * 16 * D_);

    transpose_x_kernel<<<dim3(L_ / 64, D_ / 64, B_), 256, 0, stream>>>(x, Xt);
    convert_w_kernel<<<dim3(64, 2), 256, 0, stream>>>(Wv, Wproj, Wvb, Wpb);
    qk_kernel<<<dim3(HEADS_, B_), 256, 0, stream>>>(q, Wk, qkb);
    gemm_v_mfma<<<dim3(L_ / 64, B_), 256, 0, stream>>>(Xt, Wvb, qkb, Vo, S);
    attend_kernel<<<dim3(7, 4, B_ * HEADS_), 256, 0, stream>>>(
        S, Vo, pos_emb, Wlin, Om);
    gemm_proj_mfma<<<dim3(L_ / 64, B_), 256, 0, stream>>>(Om, Wpb, out);
}

// Round 7
// 200.149 us; speedup vs baseline: 1.1525x; 1.1525x over previous
//
#include <hip/hip_runtime.h>

#define B_     16
#define D_     256
#define HEADS_ 8
#define H_     56
#define W_     56
#define L_     3136
#define LDK    40    // padded LDS row stride for 32-col bf16 tiles
#define LDQ    264   // padded LDS row stride for qk rows (256 cols)

typedef short short8 __attribute__((ext_vector_type(8)));
typedef float f32x4  __attribute__((ext_vector_type(4)));

__device__ __forceinline__ unsigned short f2bf(float f) {
    union { float f; unsigned u; } c; c.f = f;
    unsigned u = c.u;
    u += 0x7fffu + ((u >> 16) & 1u);   // RNE
    return (unsigned short)(u >> 16);
}

// ---------------------------------------------------------------------------
// x [b][c][l] fp32 -> Xt [b][l][c] bf16  (64x64 LDS tile transpose)
// ---------------------------------------------------------------------------
__global__ __launch_bounds__(256) void transpose_x_kernel(
    const float* __restrict__ x, unsigned short* __restrict__ Xt)
{
    __shared__ float tile[64][65];
    const int bb = blockIdx.z;
    const int c0 = blockIdx.y * 64;
    const int l0 = blockIdx.x * 64;
    const int t  = threadIdx.x;
    const int g4 = (t & 15) * 4;
    const int rr = t >> 4;

    const float* xb = x + ((size_t)bb * D_ + c0) * L_ + l0;
#pragma unroll
    for (int i = 0; i < 4; ++i) {
        const int c = rr + i * 16;
        float4 v = *(const float4*)(xb + (size_t)c * L_ + g4);
        *(float4*)&tile[c][g4] = v;
    }
    __syncthreads();
    unsigned short* Xb = Xt + ((size_t)bb * L_ + l0) * D_ + c0;
#pragma unroll
    for (int i = 0; i < 4; ++i) {
        const int l = rr + i * 16;
        uint2 o;
        o.x = (unsigned)f2bf(tile[g4 + 0][l]) | ((unsigned)f2bf(tile[g4 + 1][l]) << 16);
        o.y = (unsigned)f2bf(tile[g4 + 2][l]) | ((unsigned)f2bf(tile[g4 + 3][l]) << 16);
        *(uint2*)(Xb + (size_t)l * D_ + g4) = o;
    }
}

// ---------------------------------------------------------------------------
// Wv, Wproj fp32 -> bf16
// ---------------------------------------------------------------------------
__global__ __launch_bounds__(256) void convert_w_kernel(
    const float* __restrict__ w0, const float* __restrict__ w1,
    unsigned short* __restrict__ o0, unsigned short* __restrict__ o1)
{
    const float* src = blockIdx.y ? w1 : w0;
    unsigned short* dst = blockIdx.y ? o1 : o0;
    const int i = (blockIdx.x * 256 + threadIdx.x) * 4;
    float4 v = *(const float4*)(src + i);
    uint2 o;
    o.x = (unsigned)f2bf(v.x) | ((unsigned)f2bf(v.y) << 16);
    o.y = (unsigned)f2bf(v.z) | ((unsigned)f2bf(v.w) << 16);
    *(uint2*)(dst + i) = o;
}

// ---------------------------------------------------------------------------
// qk[b,h,c] = sum_n q[b,h,n]*Wk[h*32+n,c]; rows 8..15 zero (A-tile padding)
// ---------------------------------------------------------------------------
__global__ __launch_bounds__(256) void qk_kernel(
    const float* __restrict__ q, const float* __restrict__ Wk,
    unsigned short* __restrict__ qkb)
{
    const int h = blockIdx.x;
    const int b = blockIdx.y;
    const int c = threadIdx.x;
    float s = 0.f;
#pragma unroll
    for (int n = 0; n < 32; ++n)
        s = fmaf(q[b * D_ + h * 32 + n], Wk[(size_t)(h * 32 + n) * D_ + c], s);
    qkb[((size_t)b * 16 + h) * D_ + c]     = f2bf(s);
    qkb[((size_t)b * 16 + 8 + h) * D_ + c] = 0;
}

// ---------------------------------------------------------------------------
// V projection + S.  BM=256, BN=64, BK=32, 4 waves.
// A (Wv) lives in REGISTERS (loaded once, full K); only the 64x32 X tile
// goes through LDS (double-buffered, 1 barrier/kt). Per kt per thread:
// 1 ds_write_b128 + 5 ds_read_b128 + 17 MFMA  -> MFMA is the critical pipe.
// ---------------------------------------------------------------------------
__global__ __launch_bounds__(256, 2) void gemm_v_mfma(
    const unsigned short* __restrict__ Xt, const unsigned short* __restrict__ Wvb,
    const unsigned short* __restrict__ qkb,
    unsigned short* __restrict__ Vo, float* __restrict__ S)
{
    __shared__ unsigned short Xs[2][64][LDK];   // 10.2 KB
    __shared__ unsigned short Qs[16][LDQ];      // 8.45 KB

    const int bb = blockIdx.y;
    const int l0 = blockIdx.x * 64;
    const int t  = threadIdx.x;
    const int w    = t >> 6;
    const int lane = t & 63;
    const int col  = lane & 15;
    const int quad = lane >> 4;

    // stage qk once
    {
        const int r   = t >> 4;
        const int c16 = (t & 15) * 16;
        const unsigned short* src = qkb + ((size_t)bb * 16 + r) * D_ + c16;
        *(uint4*)&Qs[r][c16]     = *(const uint4*)src;
        *(uint4*)&Qs[r][c16 + 8] = *(const uint4*)(src + 8);
    }

    // A preload: wave w covers d rows [64w, 64w+64); all K in registers.
    short8 av[8][4];
    {
        const unsigned short* wv0 = Wvb + (size_t)(w * 64 + col) * D_ + quad * 8;
#pragma unroll
        for (int kt = 0; kt < 8; ++kt)
#pragma unroll
            for (int mi = 0; mi < 4; ++mi)
                av[kt][mi] = *(const short8*)(wv0 + (size_t)mi * 16 * D_ + kt * 32);
    }

    const int srow = t >> 2;         // 0..63
    const int sch  = (t & 3) * 8;    // 0,8,16,24
    const unsigned short* xg = Xt + ((size_t)bb * L_ + l0 + srow) * D_ + sch;

    f32x4 accV[4][4];
    f32x4 accS = (f32x4){0.f, 0.f, 0.f, 0.f};
#pragma unroll
    for (int mi = 0; mi < 4; ++mi)
#pragma unroll
        for (int ni = 0; ni < 4; ++ni) accV[mi][ni] = (f32x4){0.f, 0.f, 0.f, 0.f};

    uint4 pX = *(const uint4*)xg;

#pragma unroll
    for (int kt = 0; kt < 8; ++kt) {
        const int buf = kt & 1;
        *(uint4*)&Xs[buf][srow][sch] = pX;
        __syncthreads();

        if (kt < 7) pX = *(const uint4*)(xg + (kt + 1) * 32);

        short8 bx[4], aq;
        aq = *(const short8*)&Qs[col][kt * 32 + quad * 8];
#pragma unroll
        for (int ni = 0; ni < 4; ++ni)
            bx[ni] = *(const short8*)&Xs[buf][ni * 16 + col][quad * 8];

#pragma unroll
        for (int mi = 0; mi < 4; ++mi)
#pragma unroll
            for (int ni = 0; ni < 4; ++ni)
                accV[mi][ni] = __builtin_amdgcn_mfma_f32_16x16x32_bf16(
                    av[kt][mi], bx[ni], accV[mi][ni], 0, 0, 0);

        // S-MFMA: wave-uniform static select of this wave's l-chunk
        if (w == 0)
            accS = __builtin_amdgcn_mfma_f32_16x16x32_bf16(aq, bx[0], accS, 0, 0, 0);
        else if (w == 1)
            accS = __builtin_amdgcn_mfma_f32_16x16x32_bf16(aq, bx[1], accS, 0, 0, 0);
        else if (w == 2)
            accS = __builtin_amdgcn_mfma_f32_16x16x32_bf16(aq, bx[2], accS, 0, 0, 0);
        else
            accS = __builtin_amdgcn_mfma_f32_16x16x32_bf16(aq, bx[3], accS, 0, 0, 0);
    }

    // ---- V epilogue: Vo[((b*8+head)*L + l)*32 + (d&31)] ----
#pragma unroll
    for (int mi = 0; mi < 4; ++mi) {
        const int hh = w * 2 + (mi >> 1);
        const int dn = (mi & 1) * 16 + quad * 4;
#pragma unroll
        for (int ni = 0; ni < 4; ++ni) {
            unsigned short pk[4];
#pragma unroll
            for (int r = 0; r < 4; ++r) pk[r] = f2bf(accV[mi][ni][r]);
            const int l = l0 + ni * 16 + col;
            *(uint2*)(Vo + ((((size_t)(bb * HEADS_ + hh)) * L_ + l) << 5) + dn) =
                *(const uint2*)pk;
        }
    }

    // ---- S epilogue: wave w holds l-chunk ni=w; C rows 0..7 are heads ----
    if (quad < 2) {
        const int l = l0 + w * 16 + col;
#pragma unroll
        for (int r = 0; r < 4; ++r) {
            const int h = quad * 4 + r;
            S[(size_t)(bb * HEADS_ + h) * L_ + l] = accS[r];
        }
    }
}

// ---------------------------------------------------------------------------
// attend: LDS-staged, block = (8-row band, 8-ch group, b*h).
// ---------------------------------------------------------------------------
__global__ __launch_bounds__(256) void attend_kernel(
    const float* __restrict__ S, const unsigned short* __restrict__ Vo,
    const float* __restrict__ pos_emb, const float* __restrict__ Wlin,
    unsigned short* __restrict__ Om)
{
    __shared__ unsigned short Vs[10][58][8];
    __shared__ float Ss[10][58];

    const int band = blockIdx.x;
    const int half = blockIdx.y;
    const int bh   = blockIdx.z;
    const int y0   = band * 8;
    const int t    = threadIdx.x;

    const float* Sb = S + (size_t)bh * L_;
    for (int j = t; j < 580; j += 256) {
        const int row = j / 58, c = j - row * 58;
        const int gr = y0 - 1 + row, gc = c - 1;
        const bool in = (gr >= 0 && gr < H_ && gc >= 0 && gc < W_);
        Ss[row][c] = in ? Sb[gr * W_ + gc] : 0.f;
        uint4 vv = make_uint4(0u, 0u, 0u, 0u);
        if (in)
            vv = *(const uint4*)(Vo + (((size_t)bh * L_ + gr * W_ + gc) << 5) + half * 8);
        *(uint4*)&Vs[row][c][0] = vv;
    }
    __syncthreads();

    const float scale = Wlin[0] + Wlin[1] + Wlin[2] + Wlin[3];
    const float pe0 = pos_emb[0], pe1 = pos_emb[1], pe2 = pos_emb[2];
    const float pe3 = pos_emb[3], pe4 = pos_emb[4];
    const float bias[9] = {pe0, pe1, pe2, pe1, pe2, pe3, pe2, pe3, pe4};

    for (int p = t; p < 448; p += 256) {
        const int yl = p / 56, xx = p - yl * 56;
        const int lr = yl + 1, lc = xx + 1;

        float lg[9], m = -1e30f;
#pragma unroll
        for (int dy = 0; dy < 3; ++dy)
#pragma unroll
            for (int dx = 0; dx < 3; ++dx) {
                const int k = dy * 3 + dx;
                lg[k] = Ss[lr - 1 + dy][lc - 1 + dx] + bias[k];
                m = fmaxf(m, lg[k]);
            }
        float ssum = 0.f;
#pragma unroll
        for (int k = 0; k < 9; ++k) { lg[k] = __expf(lg[k] - m); ssum += lg[k]; }
        const float inv = scale / ssum;

        float om[8] = {0.f, 0.f, 0.f, 0.f, 0.f, 0.f, 0.f, 0.f};
#pragma unroll
        for (int dy = 0; dy < 3; ++dy)
#pragma unroll
            for (int dx = 0; dx < 3; ++dx) {
                const float wk = lg[dy * 3 + dx] * inv;
                const uint4 v = *(const uint4*)&Vs[lr - 1 + dy][lc - 1 + dx][0];
                const unsigned* u = (const unsigned*)&v;
#pragma unroll
                for (int i = 0; i < 4; ++i) {
                    union { unsigned uu; float f; } lo, hi;
                    lo.uu = u[i] << 16;
                    hi.uu = u[i] & 0xffff0000u;
                    om[2 * i]     = fmaf(wk, lo.f, om[2 * i]);
                    om[2 * i + 1] = fmaf(wk, hi.f, om[2 * i + 1]);
                }
            }

        unsigned short ob[8];
#pragma unroll
        for (int i = 0; i < 8; ++i) ob[i] = f2bf(om[i]);
        const int l = (y0 + yl) * W_ + xx;
        *(uint4*)(Om + (((size_t)bh * L_ + l) << 5) + half * 8) = *(const uint4*)ob;
    }
}

// ---------------------------------------------------------------------------
// out = Wproj @ Om.  Same A-in-registers structure: Wproj frags preloaded,
// only the Om tile through LDS (dbuf, 1 barrier/kt).
// ---------------------------------------------------------------------------
__global__ __launch_bounds__(256, 2) void gemm_proj_mfma(
    const unsigned short* __restrict__ Om, const unsigned short* __restrict__ Wpb,
    float* __restrict__ Out)
{
    __shared__ unsigned short Os[2][64][LDK];   // 10.2 KB

    const int bb = blockIdx.y;
    const int l0 = blockIdx.x * 64;
    const int t  = threadIdx.x;
    const int w    = t >> 6;
    const int lane = t & 63;
    const int col  = lane & 15;
    const int quad = lane >> 4;

    short8 ap[8][4];
    {
        const unsigned short* wp0 = Wpb + (size_t)(w * 64 + col) * D_ + quad * 8;
#pragma unroll
        for (int kt = 0; kt < 8; ++kt)
#pragma unroll
            for (int mi = 0; mi < 4; ++mi)
                ap[kt][mi] = *(const short8*)(wp0 + (size_t)mi * 16 * D_ + kt * 32);
    }

    const int srow = t >> 2;
    const int sch  = (t & 3) * 8;
    const unsigned short* og = Om + ((((size_t)(bb * HEADS_)) * L_ + l0 + srow) << 5) + sch;

    f32x4 acc[4][4];
#pragma unroll
    for (int mi = 0; mi < 4; ++mi)
#pragma unroll
        for (int ni = 0; ni < 4; ++ni) acc[mi][ni] = (f32x4){0.f, 0.f, 0.f, 0.f};

    uint4 pO = *(const uint4*)og;

#pragma unroll
    for (int kt = 0; kt < 8; ++kt) {
        const int buf = kt & 1;
        *(uint4*)&Os[buf][srow][sch] = pO;
        __syncthreads();

        if (kt < 7)
            pO = *(const uint4*)(og + (((size_t)(kt + 1)) * L_ << 5));

        short8 b[4];
#pragma unroll
        for (int ni = 0; ni < 4; ++ni)
            b[ni] = *(const short8*)&Os[buf][ni * 16 + col][quad * 8];

#pragma unroll
        for (int mi = 0; mi < 4; ++mi)
#pragma unroll
            for (int ni = 0; ni < 4; ++ni)
                acc[mi][ni] = __builtin_amdgcn_mfma_f32_16x16x32_bf16(
                    ap[kt][mi], b[ni], acc[mi][ni], 0, 0, 0);
    }

#pragma unroll
    for (int mi = 0; mi < 4; ++mi)
#pragma unroll
        for (int ni = 0; ni < 4; ++ni)
#pragma unroll
            for (int r = 0; r < 4; ++r) {
                const int d = w * 64 + mi * 16 + quad * 4 + r;
                const int l = l0 + ni * 16 + col;
                Out[((size_t)bb * D_ + d) * L_ + l] = acc[mi][ni][r];
            }
}

// ---------------------------------------------------------------------------
extern "C" void kernel_launch(void* const* d_in, const int* in_sizes, int n_in,
                              void* d_out, int out_size, void* d_ws, size_t ws_size,
                              hipStream_t stream)
{
    const float* x       = (const float*)d_in[0];
    const float* q       = (const float*)d_in[1];
    const float* Wk      = (const float*)d_in[2];
    const float* Wv      = (const float*)d_in[3];
    const float* pos_emb = (const float*)d_in[4];
    const float* Wlin    = (const float*)d_in[5];
    const float* Wproj   = (const float*)d_in[6];
    float* out = (float*)d_out;

    const size_t planeE = (size_t)B_ * D_ * L_;
    unsigned short* Xt  = (unsigned short*)d_ws;
    unsigned short* Vo  = Xt + planeE;
    unsigned short* Om  = Vo + planeE;
    unsigned short* Wvb = Om + planeE;
    unsigned short* Wpb = Wvb + D_ * D_;
    unsigned short* qkb = Wpb + D_ * D_;          // B*16*256
    float*          S   = (float*)(qkb + B_ * 16 * D_);

    transpose_x_kernel<<<dim3(L_ / 64, D_ / 64, B_), 256, 0, stream>>>(x, Xt);
    convert_w_kernel<<<dim3(64, 2), 256, 0, stream>>>(Wv, Wproj, Wvb, Wpb);
    qk_kernel<<<dim3(HEADS_, B_), 256, 0, stream>>>(q, Wk, qkb);
    gemm_v_mfma<<<dim3(L_ / 64, B_), 256, 0, stream>>>(Xt, Wvb, qkb, Vo, S);
    attend_kernel<<<dim3(7, 4, B_ * HEADS_), 256, 0, stream>>>(
        S, Vo, pos_emb, Wlin, Om);
    gemm_proj_mfma<<<dim3(L_ / 64, B_), 256, 0, stream>>>(Om, Wpb, out);
}